// Round 5
// baseline (185.041 us; speedup 1.0000x reference)
//
#include <hip/hip_runtime.h>
#include <hip/hip_cooperative_groups.h>
namespace cg = cooperative_groups;

// (B,N,D,H,K) = (8,128,256,128,8) — all fp32
#define PB 8
#define PN 128
#define PD 256
#define PH 128
#define PK 8
#define D2 (2*PD)  // 512
#define NT 4       // n-rows per phase-A block

struct SmA { float es[NT][PD]; float wtile[32][PH + 1]; };   // 4 KB + 16.5 KB
struct SmW { float qs[PD]; float red[256]; };                 // 2 KB
struct SmB { float wq[PH * PK]; float ais[2 * PH]; float bqs[PK]; }; // ~6.2 KB
union  SmU { SmA a; SmW w; SmB b; };

// Single cooperative kernel, grid = 520 x 256.
// Phase A (blocks 0..511): block=(b, n-quad, part). Stages its W1 half via
//   LDS-tiled transpose (32-d chunks), computes Ai rows (part 0) or Ajt (part 1).
// Phase A (blocks 512..519): Wq[h][k], bq[k].
// grid.sync()
// Phase B (blocks 0..511): k2 scoring exactly as R4 (LDS-broadcast Wq/Ai/bq).
__global__ __launch_bounds__(256, 3) void fused(
        const float* __restrict__ E,  const float* __restrict__ W1,
        const float* __restrict__ b1, const float* __restrict__ W2,
        const float* __restrict__ b2, const float* __restrict__ q,
        float* __restrict__ Ai, float* __restrict__ Ajt,
        float* __restrict__ Wq, float* __restrict__ bq,
        float* __restrict__ out)
{
    cg::grid_group grid = cg::this_grid();
    __shared__ SmU sm;
    const int blk = blockIdx.x, t = threadIdx.x;

    if (blk < 512) {
        const int b    = blk >> 6;
        const int rest = blk & 63;
        const int n0   = (rest >> 1) * NT;
        const int part = rest & 1;
        const int h    = t & (PH - 1);
        const int s    = t >> 7;                    // sub-half: picks n-pair & stage seg

        // stage 4 E rows (1024 floats, coalesced)
        const float* erow = E + (b * PN + n0) * PD;
        float* esf = &sm.a.es[0][0];
        #pragma unroll
        for (int r = 0; r < 4; ++r) esf[r * 256 + t] = erow[r * 256 + t];

        const int na = n0 + 2 * s;                  // this thread's n-pair: na, na+1
        float acca = 0.f, accb = 0.f;
        const float* w1row = W1 + h * D2 + part * PD;

        for (int dc = 0; dc < 8; ++dc) {
            __syncthreads();                        // es ready / wtile drained
            const int cb = dc * 32 + s * 16;
            #pragma unroll
            for (int qq = 0; qq < 4; ++qq) {        // lane reads 16B contiguous of its row
                float4 v = *reinterpret_cast<const float4*>(w1row + cb + qq * 4);
                const int ld = s * 16 + qq * 4;
                sm.a.wtile[ld + 0][h] = v.x;        // lanes h consecutive: conflict-free
                sm.a.wtile[ld + 1][h] = v.y;
                sm.a.wtile[ld + 2][h] = v.z;
                sm.a.wtile[ld + 3][h] = v.w;
            }
            __syncthreads();
            const int dbase = dc * 32;
            #pragma unroll
            for (int g = 0; g < 8; ++g) {
                const float w0 = sm.a.wtile[g * 4 + 0][h];
                const float w1v = sm.a.wtile[g * 4 + 1][h];
                const float w2v = sm.a.wtile[g * 4 + 2][h];
                const float w3v = sm.a.wtile[g * 4 + 3][h];
                float4 ea = *reinterpret_cast<const float4*>(&sm.a.es[2 * s + 0][dbase + g * 4]);
                float4 eb = *reinterpret_cast<const float4*>(&sm.a.es[2 * s + 1][dbase + g * 4]);
                acca = fmaf(w0, ea.x, acca); acca = fmaf(w1v, ea.y, acca);
                acca = fmaf(w2v, ea.z, acca); acca = fmaf(w3v, ea.w, acca);
                accb = fmaf(w0, eb.x, accb); accb = fmaf(w1v, eb.y, accb);
                accb = fmaf(w2v, eb.z, accb); accb = fmaf(w3v, eb.w, accb);
            }
        }

        if (part == 0) {
            const float bb = b1[h];
            Ai[(b * PN + na) * PH + h]     = acca + bb;   // coalesced over h
            Ai[(b * PN + na + 1) * PH + h] = accb + bb;
        } else {
            float2 v2 = make_float2(acca, accb);
            *reinterpret_cast<float2*>(&Ajt[(b * PH + h) * PN + na]) = v2;
        }
    } else {
        // Wq / bq: one block per k
        const int k = blk - 512;
        sm.w.qs[t] = q[k * PD + t];
        __syncthreads();
        if (t < PH) {
            float acc = 0.f;
            #pragma unroll 4
            for (int d = 0; d < PD; ++d)
                acc = fmaf(W2[d * PH + t], sm.w.qs[d], acc);   // coalesced over t=h
            Wq[t * PK + k] = acc;
        }
        sm.w.red[t] = b2[t] * sm.w.qs[t];
        __syncthreads();
        for (int st = 128; st > 0; st >>= 1) {
            if (t < st) sm.w.red[t] += sm.w.red[t + st];
            __syncthreads();
        }
        if (t == 0) bq[k] = sm.w.red[0];
    }

    grid.sync();

    if (blk < 512) {
        const int b  = blk >> 6;
        const int i0 = (blk & 63) << 1;

        *reinterpret_cast<float4*>(&sm.b.wq[t * 4]) =
            *reinterpret_cast<const float4*>(&Wq[t * 4]);
        sm.b.ais[t] = Ai[(b * PN + i0) * PH + t];
        if (t < PK) sm.b.bqs[t] = bq[t];
        __syncthreads();

        const int half = t >> 7;
        const int i = i0 + half;
        const int j = t & (PN - 1);
        const float* ail = sm.b.ais + half * PH;
        const float* aj = Ajt + b * PH * PN + j;    // lane-contiguous per h

        float acc[PK];
        #pragma unroll
        for (int k = 0; k < PK; ++k) acc[k] = sm.b.bqs[k];

        #pragma unroll 4
        for (int hh = 0; hh < PH; ++hh) {
            const float v = fmaxf(ail[hh] + aj[hh * PN], 0.f);
            float4 w0 = *reinterpret_cast<const float4*>(&sm.b.wq[hh * PK]);
            float4 w1 = *reinterpret_cast<const float4*>(&sm.b.wq[hh * PK + 4]);
            acc[0] = fmaf(v, w0.x, acc[0]); acc[1] = fmaf(v, w0.y, acc[1]);
            acc[2] = fmaf(v, w0.z, acc[2]); acc[3] = fmaf(v, w0.w, acc[3]);
            acc[4] = fmaf(v, w1.x, acc[4]); acc[5] = fmaf(v, w1.y, acc[5]);
            acc[6] = fmaf(v, w1.z, acc[6]); acc[7] = fmaf(v, w1.w, acc[7]);
        }

        #pragma unroll
        for (int k = 0; k < PK; ++k) {
            float sv = 1.f / (1.f + __expf(-acc[k]));
            if (j == i) sv = 0.f;
            out[((b * PK + k) * PN + i) * PN + j] = sv;   // coalesced over j
        }
    }
}

extern "C" void kernel_launch(void* const* d_in, const int* in_sizes, int n_in,
                              void* d_out, int out_size, void* d_ws, size_t ws_size,
                              hipStream_t stream) {
    const float* E  = (const float*)d_in[0];
    const float* W1 = (const float*)d_in[1];
    const float* b1 = (const float*)d_in[2];
    const float* W2 = (const float*)d_in[3];
    const float* b2 = (const float*)d_in[4];
    const float* q  = (const float*)d_in[5];

    float* Ai  = (float*)d_ws;                 // B*N*H
    float* Ajt = Ai + PB * PN * PH;            // B*H*N
    float* Wq  = Ajt + PB * PN * PH;           // H*K
    float* bq  = Wq + PH * PK;                 // K
    float* out = (float*)d_out;

    void* args[] = { (void*)&E, (void*)&W1, (void*)&b1, (void*)&W2, (void*)&b2,
                     (void*)&q, (void*)&Ai, (void*)&Ajt, (void*)&Wq, (void*)&bq,
                     (void*)&out };
    hipLaunchCooperativeKernel((const void*)fused, dim3(520), dim3(256),
                               args, 0, stream);
}

// Round 6
// 99.483 us; speedup vs baseline: 1.8600x; 1.8600x over previous
//
#include <hip/hip_runtime.h>

// (B,N,D,H,K) = (8,128,256,128,8) — all fp32
#define PB 8
#define PN 128
#define PD 256
#define PH 128
#define PK 8
#define D2 (2*PD)  // 512
#define NT 4       // n-rows per k1 block

// ---------------------------------------------------------------------------
// k1, blocks 0..511: block=(b, n-quad, part). Per-block LDS-tiled transpose of
//   its W1 half (32-d chunks), FMAs against LDS-staged E rows.
//   part 0 -> Ai[b][n][h] (+b1), part 1 -> Ajt[b][h][n].
// k1, blocks 512..519: Wq[h][k] = sum_d W2[d][h] q[k][d], bq[k] = b2·q[k].
// ---------------------------------------------------------------------------
__global__ __launch_bounds__(256) void k1_proj(
        const float* __restrict__ E,  const float* __restrict__ W1,
        const float* __restrict__ b1, const float* __restrict__ W2,
        const float* __restrict__ b2, const float* __restrict__ q,
        float* __restrict__ Ai, float* __restrict__ Ajt,
        float* __restrict__ Wq, float* __restrict__ bq)
{
    const int blk = blockIdx.x, t = threadIdx.x;

    if (blk < 512) {
        __shared__ float es[NT][PD];          // 4 KB
        __shared__ float wtile[32][PH + 1];   // 16.5 KB, padded: conflict-free
        const int b    = blk >> 6;
        const int rest = blk & 63;
        const int n0   = (rest >> 1) * NT;
        const int part = rest & 1;
        const int h    = t & (PH - 1);
        const int s    = t >> 7;              // picks n-pair & staging segment

        const float* erow = E + (b * PN + n0) * PD;
        float* esf = &es[0][0];
        #pragma unroll
        for (int r = 0; r < 4; ++r) esf[r * 256 + t] = erow[r * 256 + t];

        const int na = n0 + 2 * s;
        float acca = 0.f, accb = 0.f;
        const float* w1row = W1 + h * D2 + part * PD;

        for (int dc = 0; dc < 8; ++dc) {
            __syncthreads();                  // es ready / wtile drained
            const int cb = dc * 32 + s * 16;
            #pragma unroll
            for (int qq = 0; qq < 4; ++qq) {  // 16B contiguous per lane
                float4 v = *reinterpret_cast<const float4*>(w1row + cb + qq * 4);
                const int ld = s * 16 + qq * 4;
                wtile[ld + 0][h] = v.x;       // lanes consecutive in h: no conflict
                wtile[ld + 1][h] = v.y;
                wtile[ld + 2][h] = v.z;
                wtile[ld + 3][h] = v.w;
            }
            __syncthreads();
            const int dbase = dc * 32;
            #pragma unroll
            for (int g = 0; g < 8; ++g) {
                const float w0 = wtile[g * 4 + 0][h];
                const float w1v = wtile[g * 4 + 1][h];
                const float w2v = wtile[g * 4 + 2][h];
                const float w3v = wtile[g * 4 + 3][h];
                float4 ea = *reinterpret_cast<const float4*>(&es[2 * s + 0][dbase + g * 4]);
                float4 eb = *reinterpret_cast<const float4*>(&es[2 * s + 1][dbase + g * 4]);
                acca = fmaf(w0, ea.x, acca); acca = fmaf(w1v, ea.y, acca);
                acca = fmaf(w2v, ea.z, acca); acca = fmaf(w3v, ea.w, acca);
                accb = fmaf(w0, eb.x, accb); accb = fmaf(w1v, eb.y, accb);
                accb = fmaf(w2v, eb.z, accb); accb = fmaf(w3v, eb.w, accb);
            }
        }

        if (part == 0) {
            const float bb = b1[h];
            Ai[(b * PN + na) * PH + h]     = acca + bb;   // coalesced over h
            Ai[(b * PN + na + 1) * PH + h] = accb + bb;
        } else {
            *reinterpret_cast<float2*>(&Ajt[(b * PH + h) * PN + na]) =
                make_float2(acca, accb);
        }
    } else {
        __shared__ float qs[PD];
        __shared__ float red[256];
        const int k = blk - 512;
        qs[t] = q[k * PD + t];
        __syncthreads();
        if (t < PH) {
            float acc = 0.f;
            #pragma unroll 4
            for (int d = 0; d < PD; ++d)
                acc = fmaf(W2[d * PH + t], qs[d], acc);   // coalesced over t=h
            Wq[t * PK + k] = acc;                          // [h][k]
        }
        red[t] = b2[t] * qs[t];
        __syncthreads();
        for (int st = 128; st > 0; st >>= 1) {
            if (t < st) red[t] += red[t + st];
            __syncthreads();
        }
        if (t == 0) bq[k] = red[0];
    }
}

// ---------------------------------------------------------------------------
// k2: block = (b, i-pair), 256 threads: i = i0 + (t>>7), j = t&127.
// Wq/bq/Ai staged in LDS (broadcast, b128 for Wq rows); Ajt coalesced over j.
// ---------------------------------------------------------------------------
__global__ __launch_bounds__(256) void k2_score(
        const float* __restrict__ Ai, const float* __restrict__ Ajt,
        const float* __restrict__ Wq, const float* __restrict__ bq,
        float* __restrict__ out)
{
    __shared__ float wq[PH * PK];
    __shared__ float ais[2 * PH];
    __shared__ float bqs[PK];

    const int blk = blockIdx.x, t = threadIdx.x;
    const int b  = blk >> 6;
    const int i0 = (blk & 63) << 1;

    *reinterpret_cast<float4*>(&wq[t * 4]) =
        *reinterpret_cast<const float4*>(&Wq[t * 4]);
    ais[t] = Ai[(b * PN + i0) * PH + t];
    if (t < PK) bqs[t] = bq[t];
    __syncthreads();

    const int half = t >> 7;
    const int i = i0 + half;
    const int j = t & (PN - 1);
    const float* ail = ais + half * PH;
    const float* aj = Ajt + b * PH * PN + j;    // lane-contiguous per h

    float acc[PK];
    #pragma unroll
    for (int k = 0; k < PK; ++k) acc[k] = bqs[k];

    #pragma unroll 4
    for (int h = 0; h < PH; ++h) {
        const float v = fmaxf(ail[h] + aj[h * PN], 0.f);
        float4 w0 = *reinterpret_cast<const float4*>(&wq[h * PK]);
        float4 w1 = *reinterpret_cast<const float4*>(&wq[h * PK + 4]);
        acc[0] = fmaf(v, w0.x, acc[0]); acc[1] = fmaf(v, w0.y, acc[1]);
        acc[2] = fmaf(v, w0.z, acc[2]); acc[3] = fmaf(v, w0.w, acc[3]);
        acc[4] = fmaf(v, w1.x, acc[4]); acc[5] = fmaf(v, w1.y, acc[5]);
        acc[6] = fmaf(v, w1.z, acc[6]); acc[7] = fmaf(v, w1.w, acc[7]);
    }

    #pragma unroll
    for (int k = 0; k < PK; ++k) {
        float s = 1.f / (1.f + __expf(-acc[k]));
        if (j == i) s = 0.f;
        out[((b * PK + k) * PN + i) * PN + j] = s;   // coalesced over j
    }
}

extern "C" void kernel_launch(void* const* d_in, const int* in_sizes, int n_in,
                              void* d_out, int out_size, void* d_ws, size_t ws_size,
                              hipStream_t stream) {
    const float* E  = (const float*)d_in[0];
    const float* W1 = (const float*)d_in[1];
    const float* b1 = (const float*)d_in[2];
    const float* W2 = (const float*)d_in[3];
    const float* b2 = (const float*)d_in[4];
    const float* q  = (const float*)d_in[5];

    float* Ai  = (float*)d_ws;                 // B*N*H
    float* Ajt = Ai + PB * PN * PH;            // B*H*N
    float* Wq  = Ajt + PB * PN * PH;           // H*K
    float* bq  = Wq + PH * PK;                 // K

    k1_proj<<<520, 256, 0, stream>>>(E, W1, b1, W2, b2, q, Ai, Ajt, Wq, bq);
    k2_score<<<PB * PN / 2, 256, 0, stream>>>(Ai, Ajt, Wq, bq, (float*)d_out);
}

// Round 8
// 97.051 us; speedup vs baseline: 1.9066x; 1.0251x over previous
//
#include <hip/hip_runtime.h>

// (B,N,D,H,K) = (8,128,256,128,8) — all fp32
#define PB 8
#define PN 128
#define PD 256
#define PH 128
#define PK 8
#define D2 (2*PD)  // 512
#define NT 4       // n-rows per k1 block

// ---------------------------------------------------------------------------
// k1, blocks 0..511: block=(b, n-quad, part). LDS transpose of its W1 half in
//   64-d chunks (8 barriers total), FMAs against LDS-staged E rows.
//   part 0 -> Ai[b][n][h] (+b1), part 1 -> Ajt[b][h][n].
// k1, blocks 512..519: Wq[h][k], bq[k].
// ---------------------------------------------------------------------------
__global__ __launch_bounds__(256, 2) void k1_proj(
        const float* __restrict__ E,  const float* __restrict__ W1,
        const float* __restrict__ b1, const float* __restrict__ W2,
        const float* __restrict__ b2, const float* __restrict__ q,
        float* __restrict__ Ai, float* __restrict__ Ajt,
        float* __restrict__ Wq, float* __restrict__ bq)
{
    const int blk = blockIdx.x, t = threadIdx.x;

    if (blk < 512) {
        __shared__ float es[NT][PD];          // 4 KB
        __shared__ float wtile[64][PH + 1];   // 33 KB, padded: conflict-free
        const int b    = blk >> 6;
        const int rest = blk & 63;
        const int n0   = (rest >> 1) * NT;
        const int part = rest & 1;
        const int h    = t & (PH - 1);
        const int s    = t >> 7;              // picks n-pair & staging segment

        const float* erow = E + (b * PN + n0) * PD;
        float* esf = &es[0][0];
        #pragma unroll
        for (int r = 0; r < 4; ++r) esf[r * 256 + t] = erow[r * 256 + t];

        const int na = n0 + 2 * s;
        float acca = 0.f, accb = 0.f;
        const float* w1row = W1 + h * D2 + part * PD;

        for (int dc = 0; dc < 4; ++dc) {      // 64-d chunks
            __syncthreads();                  // es ready / wtile drained
            const int cb = dc * 64 + s * 32;
            #pragma unroll
            for (int qq = 0; qq < 8; ++qq) {  // 16B contiguous per lane
                float4 v = *reinterpret_cast<const float4*>(w1row + cb + qq * 4);
                const int ld = s * 32 + qq * 4;
                wtile[ld + 0][h] = v.x;       // lanes consecutive in h: no conflict
                wtile[ld + 1][h] = v.y;
                wtile[ld + 2][h] = v.z;
                wtile[ld + 3][h] = v.w;
            }
            __syncthreads();
            const int dbase = dc * 64;
            #pragma unroll
            for (int g = 0; g < 16; ++g) {
                const float w0  = wtile[g * 4 + 0][h];
                const float w1v = wtile[g * 4 + 1][h];
                const float w2v = wtile[g * 4 + 2][h];
                const float w3v = wtile[g * 4 + 3][h];
                float4 ea = *reinterpret_cast<const float4*>(&es[2 * s + 0][dbase + g * 4]);
                float4 eb = *reinterpret_cast<const float4*>(&es[2 * s + 1][dbase + g * 4]);
                acca = fmaf(w0, ea.x, acca); acca = fmaf(w1v, ea.y, acca);
                acca = fmaf(w2v, ea.z, acca); acca = fmaf(w3v, ea.w, acca);
                accb = fmaf(w0, eb.x, accb); accb = fmaf(w1v, eb.y, accb);
                accb = fmaf(w2v, eb.z, accb); accb = fmaf(w3v, eb.w, accb);
            }
        }

        if (part == 0) {
            const float bb = b1[h];
            Ai[(b * PN + na) * PH + h]     = acca + bb;   // coalesced over h
            Ai[(b * PN + na + 1) * PH + h] = accb + bb;
        } else {
            *reinterpret_cast<float2*>(&Ajt[(b * PH + h) * PN + na]) =
                make_float2(acca, accb);
        }
    } else {
        __shared__ float qs[PD];
        __shared__ float red[256];
        const int k = blk - 512;
        qs[t] = q[k * PD + t];
        __syncthreads();
        if (t < PH) {
            float acc = 0.f;
            #pragma unroll 4
            for (int d = 0; d < PD; ++d)
                acc = fmaf(W2[d * PH + t], qs[d], acc);   // coalesced over t=h
            Wq[t * PK + k] = acc;                          // [h][k]
        }
        red[t] = b2[t] * qs[t];
        __syncthreads();
        for (int st = 128; st > 0; st >>= 1) {
            if (t < st) red[t] += red[t + st];
            __syncthreads();
        }
        if (t == 0) bq[k] = red[0];
    }
}

// ---------------------------------------------------------------------------
// k2: split-k. 1024 blocks = (b, 64 i-pairs, 2 k-halves), 256 threads.
//   b = blk>>7; r = blk&127; i0 = (r>>1)<<1; kh = r&1.
//   i = i0 + (t>>7), j = t&127, k in [4*kh, 4*kh+4).
// Wq-half/bq/Ai staged in LDS (broadcast); Ajt coalesced over j.
// ---------------------------------------------------------------------------
__global__ __launch_bounds__(256) void k2_score(
        const float* __restrict__ Ai, const float* __restrict__ Ajt,
        const float* __restrict__ Wq, const float* __restrict__ bq,
        float* __restrict__ out)
{
    __shared__ float wqh[PH * 4];              // this block's k-half of Wq
    __shared__ float ais[2 * PH];
    __shared__ float bqs[4];

    const int blk = blockIdx.x, t = threadIdx.x;
    const int b  = blk >> 7;                   // [0,8)
    const int r  = blk & 127;                  // 64 i-pairs x 2 k-halves
    const int i0 = (r >> 1) << 1;
    const int kh = r & 1;

    if (t < PH)                                 // 128 lanes: one f4 per h row
        *reinterpret_cast<float4*>(&wqh[t * 4]) =
            *reinterpret_cast<const float4*>(&Wq[t * PK + 4 * kh]);
    ais[t] = Ai[(b * PN + i0) * PH + t];        // rows i0, i0+1 back-to-back
    if (t < 4) bqs[t] = bq[4 * kh + t];
    __syncthreads();

    const int half = t >> 7;
    const int i = i0 + half;
    const int j = t & (PN - 1);
    const float* ail = ais + half * PH;
    const float* aj = Ajt + b * PH * PN + j;    // lane-contiguous per h

    float acc[4];
    #pragma unroll
    for (int k = 0; k < 4; ++k) acc[k] = bqs[k];

    #pragma unroll 8
    for (int h = 0; h < PH; ++h) {
        const float v = fmaxf(ail[h] + aj[h * PN], 0.f);
        float4 w0 = *reinterpret_cast<const float4*>(&wqh[h * 4]);  // ds_b128 bcast
        acc[0] = fmaf(v, w0.x, acc[0]); acc[1] = fmaf(v, w0.y, acc[1]);
        acc[2] = fmaf(v, w0.z, acc[2]); acc[3] = fmaf(v, w0.w, acc[3]);
    }

    #pragma unroll
    for (int k = 0; k < 4; ++k) {
        float s = 1.f / (1.f + __expf(-acc[k]));
        if (j == i) s = 0.f;
        out[((b * PK + 4 * kh + k) * PN + i) * PN + j] = s;  // coalesced over j
    }
}

extern "C" void kernel_launch(void* const* d_in, const int* in_sizes, int n_in,
                              void* d_out, int out_size, void* d_ws, size_t ws_size,
                              hipStream_t stream) {
    const float* E  = (const float*)d_in[0];
    const float* W1 = (const float*)d_in[1];
    const float* b1 = (const float*)d_in[2];
    const float* W2 = (const float*)d_in[3];
    const float* b2 = (const float*)d_in[4];
    const float* q  = (const float*)d_in[5];

    float* Ai  = (float*)d_ws;                 // B*N*H
    float* Ajt = Ai + PB * PN * PH;            // B*H*N
    float* Wq  = Ajt + PB * PN * PH;           // H*K
    float* bq  = Wq + PH * PK;                 // K

    k1_proj<<<520, 256, 0, stream>>>(E, W1, b1, W2, b2, q, Ai, Ajt, Wq, bq);
    k2_score<<<PB * PN, 256, 0, stream>>>(Ai, Ajt, Wq, bq, (float*)d_out);
}